// Round 6
// baseline (45.280 us; speedup 1.0000x reference)
//
#include <hip/hip_runtime.h>
#include <hip/hip_cooperative_groups.h>

namespace cg = cooperative_groups;

#define B_ 8
#define K_ 32
#define C_ 32
#define H_ 128
#define W_ 128
#define V_ (K_ * (C_ / 2))        // 512 vertices per batch
#define RPB 4                     // rows per block
#define NBLK (B_ * H_ / RPB)      // 256 blocks

// Single cooperative kernel: per block = (batch, 4 rows).
//  Phase 1: gather verts -> LDS; lane-per-edge parity masks; per-pixel MSE
//           over 4 rows; block partial -> bsums[blk] (overwrite, no init).
//  grid.sync()
//  Phase 2: block 0 reduces 256 partials (double) + mask sum, writes scalar.
__global__ void __launch_bounds__(W_) fused_coop_kernel(
        const float* __restrict__ output,
        const float* __restrict__ mask,
        const int*   __restrict__ ind,
        const float* __restrict__ centers,
        const float* __restrict__ target,
        float* __restrict__ out,
        float* __restrict__ bsums) {
    const int blk = blockIdx.x;
    const int b   = blk >> 5;               // / (H_/RPB)
    const int r0  = (blk & 31) * RPB;
    const int l   = threadIdx.x;            // 0..127

    __shared__ float vx[V_];
    __shared__ float vy[V_];

    // ---- gather: lane l produces verts 4l..4l+3 (all same k = l>>2) ----
    {
        const int k   = l >> 2;
        const int pos = ind[b * K_ + k];
        const float cx = centers[(b * K_ + k) * 2 + 0];
        const float cy = centers[(b * K_ + k) * 2 + 1];
        const int v0  = 4 * l;
        const int c2b = v0 & 15;
        const float* ob = output + (size_t)b * C_ * (H_ * W_) + pos;
        #pragma unroll
        for (int j = 0; j < 4; ++j) {
            const int c2 = c2b + j;
            vx[v0 + j] = truncf(__fadd_rn(ob[(size_t)(2 * c2)     * (H_ * W_)], cx));
            vy[v0 + j] = truncf(__fadd_rn(ob[(size_t)(2 * c2 + 1) * (H_ * W_)], cy));
        }
    }
    __syncthreads();

    __shared__ unsigned long long wlo[2], whi[2];
    __shared__ float fs[2];
    const int w = l >> 6;
    float s = 0.0f;

    for (int rr = 0; rr < RPB; ++rr) {
        const int row = r0 + rr;
        const float py = (float)row;
        unsigned long long mlo = 0ull, mhi = 0ull;
        const int e0 = 4 * l;
        #pragma unroll
        for (int j = 0; j < 4; ++j) {
            const int e  = e0 + j;
            const int en = (e + 1) & (V_ - 1);
            const float y1 = vy[e];
            const float y2 = vy[en];
            if ((y1 <= py) != (y2 <= py)) {          // dy != 0 guaranteed
                const float x1 = vx[e];
                const float x2 = vx[en];
                const float t    = __fdiv_rn(__fsub_rn(py, y1), __fsub_rn(y2, y1));
                const float xint = __fadd_rn(x1, __fmul_rn(t, __fsub_rn(x2, x1)));
                // #{ integer px in [0,128) : px < xint } == clamp(ceil(xint),0,128)
                int c = (int)ceilf(xint);
                c = c < 0 ? 0 : (c > 128 ? 128 : c);
                unsigned long long lo, hi;
                if (c >= 64) {
                    lo = ~0ull;
                    hi = (c >= 128) ? ~0ull : ((1ull << (c - 64)) - 1ull);
                } else {
                    lo = (1ull << c) - 1ull;
                    hi = 0ull;
                }
                mlo ^= lo;
                mhi ^= hi;
            }
        }
        // XOR-reduce across the wave, then across the two waves
        #pragma unroll
        for (int off = 32; off > 0; off >>= 1) {
            mlo ^= __shfl_xor(mlo, off, 64);
            mhi ^= __shfl_xor(mhi, off, 64);
        }
        if ((l & 63) == 0) { wlo[w] = mlo; whi[w] = mhi; }
        __syncthreads();
        const unsigned long long lo = wlo[0] ^ wlo[1];
        const unsigned long long hi = whi[0] ^ whi[1];

        const int bit = (l < 64) ? (int)((lo >> l) & 1ull)
                                 : (int)((hi >> (l - 64)) & 1ull);
        const float inside = bit ? 255.0f : 0.0f;
        const float tgt = target[((size_t)b * H_ + row) * W_ + l];
        const float d = __fsub_rn(inside, tgt);
        s = __fadd_rn(s, __fmul_rn(d, d));
        __syncthreads();   // WAR: next row rewrites wlo/whi
    }

    #pragma unroll
    for (int off = 32; off > 0; off >>= 1) s += __shfl_down(s, off, 64);
    if ((l & 63) == 0) fs[w] = s;
    __syncthreads();
    if (l == 0) bsums[blk] = fs[0] + fs[1];

    // ---- grid-wide barrier, then block 0 finalizes ----
    cg::this_grid().sync();

    if (blk == 0) {
        double sdv = (double)bsums[l] + (double)bsums[l + 128];  // NBLK==256
        float  smv = mask[l] + mask[l + 128];                    // B_*K_==256
        #pragma unroll
        for (int off = 32; off > 0; off >>= 1) {
            sdv += __shfl_down(sdv, off, 64);
            smv += __shfl_down(smv, off, 64);
        }
        __shared__ double sdw[2];
        __shared__ float  smw[2];
        if ((l & 63) == 0) { sdw[w] = sdv; smw[w] = smv; }
        __syncthreads();
        if (l == 0) {
            const double sum  = sdw[0] + sdw[1];
            const float  msum = smw[0] + smw[1];
            const float denomf = __fadd_rn(__fmul_rn(msum, (float)C_), 0.0001f);
            out[0] = (float)(sum / (double)(H_ * W_) / (double)denomf);
        }
    }
}

extern "C" void kernel_launch(void* const* d_in, const int* in_sizes, int n_in,
                              void* d_out, int out_size, void* d_ws, size_t ws_size,
                              hipStream_t stream) {
    const float* output  = (const float*)d_in[0];
    const float* mask    = (const float*)d_in[1];
    const int*   ind     = (const int*)d_in[2];
    const float* target  = (const float*)d_in[3];
    const float* centers = (const float*)d_in[4];
    float* out   = (float*)d_out;
    float* bsums = (float*)d_ws;   // 256 floats, fully overwritten every call

    void* args[] = { (void*)&output, (void*)&mask, (void*)&ind,
                     (void*)&centers, (void*)&target, (void*)&out,
                     (void*)&bsums };
    hipLaunchCooperativeKernel((void*)fused_coop_kernel,
                               dim3(NBLK), dim3(W_), args, 0, stream);
}

// Round 7
// 15.742 us; speedup vs baseline: 2.8763x; 2.8763x over previous
//
#include <hip/hip_runtime.h>

#define B_ 8
#define K_ 32
#define C_ 32
#define H_ 128
#define W_ 128
#define V_ (K_ * (C_ / 2))        // 512 vertices per batch
#define RPB 4                     // rows per block
#define NBLK (B_ * H_ / RPB)      // 256 blocks
#define MAGIC 0x7C3A5F11E9D24B87ull

// Single plain kernel node. Per block = (batch, 4 rows):
//   raster partial -> bsums[blk] (agent-scope store), release-store sig[blk]=MAGIC.
// Block 0 then polls all 256 sig tags (parallel, acquire agent-scope),
// reduces partials in a FIXED tree (bit-deterministic), writes the scalar,
// and zeroes sig so the next replay starts clean. Poison-proof: 0xAA..AA and
// arbitrary garbage != MAGIC (64-bit).
__global__ void __launch_bounds__(W_) fused_flag_kernel(
        const float* __restrict__ output,
        const float* __restrict__ mask,
        const int*   __restrict__ ind,
        const float* __restrict__ centers,
        const float* __restrict__ target,
        float* __restrict__ out,
        float* __restrict__ bsums,
        unsigned long long* __restrict__ sig) {
    const int blk = blockIdx.x;
    const int b   = blk >> 5;               // / (H_/RPB)
    const int r0  = (blk & 31) * RPB;
    const int l   = threadIdx.x;            // 0..127

    __shared__ float vx[V_];
    __shared__ float vy[V_];

    // ---- gather: lane l produces verts 4l..4l+3 (all same k = l>>2) ----
    {
        const int k   = l >> 2;
        const int pos = ind[b * K_ + k];
        const float cx = centers[(b * K_ + k) * 2 + 0];
        const float cy = centers[(b * K_ + k) * 2 + 1];
        const int v0  = 4 * l;
        const int c2b = v0 & 15;
        const float* ob = output + (size_t)b * C_ * (H_ * W_) + pos;
        #pragma unroll
        for (int j = 0; j < 4; ++j) {
            const int c2 = c2b + j;
            vx[v0 + j] = truncf(__fadd_rn(ob[(size_t)(2 * c2)     * (H_ * W_)], cx));
            vy[v0 + j] = truncf(__fadd_rn(ob[(size_t)(2 * c2 + 1) * (H_ * W_)], cy));
        }
    }
    __syncthreads();

    __shared__ unsigned long long wlo[2], whi[2];
    __shared__ float fs[2];
    const int w = l >> 6;
    float s = 0.0f;

    for (int rr = 0; rr < RPB; ++rr) {
        const int row = r0 + rr;
        const float py = (float)row;
        unsigned long long mlo = 0ull, mhi = 0ull;
        const int e0 = 4 * l;
        #pragma unroll
        for (int j = 0; j < 4; ++j) {
            const int e  = e0 + j;
            const int en = (e + 1) & (V_ - 1);
            const float y1 = vy[e];
            const float y2 = vy[en];
            if ((y1 <= py) != (y2 <= py)) {          // dy != 0 guaranteed
                const float x1 = vx[e];
                const float x2 = vx[en];
                const float t    = __fdiv_rn(__fsub_rn(py, y1), __fsub_rn(y2, y1));
                const float xint = __fadd_rn(x1, __fmul_rn(t, __fsub_rn(x2, x1)));
                // #{ integer px in [0,128) : px < xint } == clamp(ceil(xint),0,128)
                int c = (int)ceilf(xint);
                c = c < 0 ? 0 : (c > 128 ? 128 : c);
                unsigned long long lo, hi;
                if (c >= 64) {
                    lo = ~0ull;
                    hi = (c >= 128) ? ~0ull : ((1ull << (c - 64)) - 1ull);
                } else {
                    lo = (1ull << c) - 1ull;
                    hi = 0ull;
                }
                mlo ^= lo;
                mhi ^= hi;
            }
        }
        #pragma unroll
        for (int off = 32; off > 0; off >>= 1) {
            mlo ^= __shfl_xor(mlo, off, 64);
            mhi ^= __shfl_xor(mhi, off, 64);
        }
        if ((l & 63) == 0) { wlo[w] = mlo; whi[w] = mhi; }
        __syncthreads();
        const unsigned long long lo = wlo[0] ^ wlo[1];
        const unsigned long long hi = whi[0] ^ whi[1];

        const int bit = (l < 64) ? (int)((lo >> l) & 1ull)
                                 : (int)((hi >> (l - 64)) & 1ull);
        const float inside = bit ? 255.0f : 0.0f;
        const float tgt = target[((size_t)b * H_ + row) * W_ + l];
        const float d = __fsub_rn(inside, tgt);
        s = __fadd_rn(s, __fmul_rn(d, d));
        __syncthreads();   // WAR: next row rewrites wlo/whi
    }

    #pragma unroll
    for (int off = 32; off > 0; off >>= 1) s += __shfl_down(s, off, 64);
    if ((l & 63) == 0) fs[w] = s;
    __syncthreads();

    // ---- publish partial, signal ----
    if (l == 0) {
        const float partial = fs[0] + fs[1];
        __hip_atomic_store(&bsums[blk], partial,
                           __ATOMIC_RELAXED, __HIP_MEMORY_SCOPE_AGENT);
        __hip_atomic_store(&sig[blk], (unsigned long long)MAGIC,
                           __ATOMIC_RELEASE, __HIP_MEMORY_SCOPE_AGENT);
    }
    if (blk != 0) return;

    // ---- block 0: finalize ----
    // mask sum first (overlaps with other blocks finishing)
    __shared__ float smw[2];
    {
        float smv = mask[l] + mask[l + 128];            // B_*K_ == 256
        #pragma unroll
        for (int off = 32; off > 0; off >>= 1) smv += __shfl_down(smv, off, 64);
        if ((l & 63) == 0) smw[w] = smv;
    }

    // poll all 256 tags (each lane watches 2)
    for (;;) {
        const unsigned long long t0 = __hip_atomic_load(
            &sig[l], __ATOMIC_ACQUIRE, __HIP_MEMORY_SCOPE_AGENT);
        const unsigned long long t1 = __hip_atomic_load(
            &sig[l + 128], __ATOMIC_ACQUIRE, __HIP_MEMORY_SCOPE_AGENT);
        if (__syncthreads_and((t0 == MAGIC) && (t1 == MAGIC))) break;
    }

    // deterministic fixed-tree reduction of 256 partials in double
    double sdv = (double)__hip_atomic_load(&bsums[l], __ATOMIC_RELAXED,
                                           __HIP_MEMORY_SCOPE_AGENT)
               + (double)__hip_atomic_load(&bsums[l + 128], __ATOMIC_RELAXED,
                                           __HIP_MEMORY_SCOPE_AGENT);
    #pragma unroll
    for (int off = 32; off > 0; off >>= 1) sdv += __shfl_down(sdv, off, 64);
    __shared__ double sdw[2];
    if ((l & 63) == 0) sdw[w] = sdv;
    __syncthreads();
    if (l == 0) {
        const double sum  = sdw[0] + sdw[1];
        const float  msum = smw[0] + smw[1];
        const float denomf = __fadd_rn(__fmul_rn(msum, (float)C_), 0.0001f);
        out[0] = (float)(sum / (double)(H_ * W_) / (double)denomf);
    }

    // reset tags so the next replay starts clean
    __hip_atomic_store(&sig[l], 0ull, __ATOMIC_RELAXED, __HIP_MEMORY_SCOPE_AGENT);
    __hip_atomic_store(&sig[l + 128], 0ull, __ATOMIC_RELAXED, __HIP_MEMORY_SCOPE_AGENT);
}

extern "C" void kernel_launch(void* const* d_in, const int* in_sizes, int n_in,
                              void* d_out, int out_size, void* d_ws, size_t ws_size,
                              hipStream_t stream) {
    const float* output  = (const float*)d_in[0];
    const float* mask    = (const float*)d_in[1];
    const int*   ind     = (const int*)d_in[2];
    const float* target  = (const float*)d_in[3];
    const float* centers = (const float*)d_in[4];
    float* out = (float*)d_out;

    float* bsums            = (float*)d_ws;                       // 1 KB
    unsigned long long* sig = (unsigned long long*)((char*)d_ws + 2048); // 2 KB

    fused_flag_kernel<<<NBLK, W_, 0, stream>>>(
        output, mask, ind, centers, target, out, bsums, sig);
}

// Round 8
// 14.140 us; speedup vs baseline: 3.2022x; 1.1133x over previous
//
#include <hip/hip_runtime.h>

#define B_ 8
#define K_ 32
#define C_ 32
#define H_ 128
#define W_ 128
#define V_ (K_ * (C_ / 2))        // 512 vertices per batch
#define RPB 4                     // rows per block
#define NBLK (B_ * H_ / RPB)      // 256 blocks

// ---------------------------------------------------------------------------
// Kernel 1: per block = (batch, 4 rows).
//  - gather batch's 512 verts into LDS (4 verts/lane, scattered L2 reads)
//  - per row: lane-per-edge (4 edges/lane) -> crossing cutoff c ->
//    128-bit pixel parity mask; XOR-reduce across block -> row bitmap
//  - per-pixel squared error vs target, accumulated over 4 rows
//  - block sum -> bsums[blk] (overwritten every call; no init needed)
// ---------------------------------------------------------------------------
__global__ void __launch_bounds__(W_) raster_kernel(
        const float* __restrict__ output,
        const int*   __restrict__ ind,
        const float* __restrict__ centers,
        const float* __restrict__ target,
        float* __restrict__ bsums) {
    const int blk = blockIdx.x;
    const int b   = blk >> 5;               // / (H_/RPB)
    const int r0  = (blk & 31) * RPB;
    const int l   = threadIdx.x;            // 0..127

    __shared__ float vx[V_];
    __shared__ float vy[V_];

    // ---- gather: lane l produces verts 4l..4l+3 (all same k = l>>2) ----
    {
        const int k   = l >> 2;
        const int pos = ind[b * K_ + k];
        const float cx = centers[(b * K_ + k) * 2 + 0];
        const float cy = centers[(b * K_ + k) * 2 + 1];
        const int v0  = 4 * l;
        const int c2b = v0 & 15;
        const float* ob = output + (size_t)b * C_ * (H_ * W_) + pos;
        #pragma unroll
        for (int j = 0; j < 4; ++j) {
            const int c2 = c2b + j;
            vx[v0 + j] = truncf(__fadd_rn(ob[(size_t)(2 * c2)     * (H_ * W_)], cx));
            vy[v0 + j] = truncf(__fadd_rn(ob[(size_t)(2 * c2 + 1) * (H_ * W_)], cy));
        }
    }
    __syncthreads();

    __shared__ unsigned long long wlo[2], whi[2];
    __shared__ float fs[2];
    const int w = l >> 6;
    float s = 0.0f;

    for (int rr = 0; rr < RPB; ++rr) {
        const int row = r0 + rr;
        const float py = (float)row;
        unsigned long long mlo = 0ull, mhi = 0ull;
        const int e0 = 4 * l;
        #pragma unroll
        for (int j = 0; j < 4; ++j) {
            const int e  = e0 + j;
            const int en = (e + 1) & (V_ - 1);
            const float y1 = vy[e];
            const float y2 = vy[en];
            if ((y1 <= py) != (y2 <= py)) {          // dy != 0 guaranteed
                const float x1 = vx[e];
                const float x2 = vx[en];
                const float t    = __fdiv_rn(__fsub_rn(py, y1), __fsub_rn(y2, y1));
                const float xint = __fadd_rn(x1, __fmul_rn(t, __fsub_rn(x2, x1)));
                // #{ integer px in [0,128) : px < xint } == clamp(ceil(xint),0,128)
                int c = (int)ceilf(xint);
                c = c < 0 ? 0 : (c > 128 ? 128 : c);
                unsigned long long lo, hi;
                if (c >= 64) {
                    lo = ~0ull;
                    hi = (c >= 128) ? ~0ull : ((1ull << (c - 64)) - 1ull);
                } else {
                    lo = (1ull << c) - 1ull;
                    hi = 0ull;
                }
                mlo ^= lo;
                mhi ^= hi;
            }
        }
        // XOR-reduce across the wave, then across the two waves
        #pragma unroll
        for (int off = 32; off > 0; off >>= 1) {
            mlo ^= __shfl_xor(mlo, off, 64);
            mhi ^= __shfl_xor(mhi, off, 64);
        }
        if ((l & 63) == 0) { wlo[w] = mlo; whi[w] = mhi; }
        __syncthreads();
        const unsigned long long lo = wlo[0] ^ wlo[1];
        const unsigned long long hi = whi[0] ^ whi[1];

        const int bit = (l < 64) ? (int)((lo >> l) & 1ull)
                                 : (int)((hi >> (l - 64)) & 1ull);
        const float inside = bit ? 255.0f : 0.0f;
        const float tgt = target[((size_t)b * H_ + row) * W_ + l];
        const float d = __fsub_rn(inside, tgt);
        s = __fadd_rn(s, __fmul_rn(d, d));
        __syncthreads();   // WAR: next row rewrites wlo/whi
    }

    #pragma unroll
    for (int off = 32; off > 0; off >>= 1) s += __shfl_down(s, off, 64);
    if ((l & 63) == 0) fs[w] = s;
    __syncthreads();
    if (l == 0) bsums[blk] = fs[0] + fs[1];
}

// ---------------------------------------------------------------------------
// Kernel 2: deterministic finalize — sum 256 block sums (double) + mask sum,
// write scalar. Everything overwritten each call; no state carried.
// ---------------------------------------------------------------------------
__global__ void __launch_bounds__(256) finalize_kernel(
        const float* __restrict__ bsums,
        const float* __restrict__ mask,
        float* __restrict__ out) {
    __shared__ double sd[256];
    __shared__ float  sm[256];
    sd[threadIdx.x] = (double)bsums[threadIdx.x];   // NBLK == 256
    sm[threadIdx.x] = mask[threadIdx.x];            // B_*K_ == 256
    __syncthreads();
    for (int off = 128; off > 0; off >>= 1) {
        if (threadIdx.x < off) {
            sd[threadIdx.x] += sd[threadIdx.x + off];
            sm[threadIdx.x] += sm[threadIdx.x + off];
        }
        __syncthreads();
    }
    if (threadIdx.x == 0) {
        const float denomf = __fadd_rn(__fmul_rn(sm[0], (float)C_), 0.0001f);
        out[0] = (float)(sd[0] / (double)(H_ * W_) / (double)denomf);
    }
}

extern "C" void kernel_launch(void* const* d_in, const int* in_sizes, int n_in,
                              void* d_out, int out_size, void* d_ws, size_t ws_size,
                              hipStream_t stream) {
    const float* output  = (const float*)d_in[0];
    const float* mask    = (const float*)d_in[1];
    const int*   ind     = (const int*)d_in[2];
    const float* target  = (const float*)d_in[3];
    const float* centers = (const float*)d_in[4];
    float* out = (float*)d_out;

    float* bsums = (float*)d_ws;   // 256 floats, fully overwritten every call

    raster_kernel<<<NBLK, W_, 0, stream>>>(output, ind, centers, target, bsums);
    finalize_kernel<<<1, 256, 0, stream>>>(bsums, mask, out);
}